// Round 1
// baseline (336.696 us; speedup 1.0000x reference)
//
#include <hip/hip_runtime.h>
#include <hip/hip_bf16.h>

#define N2 16384
#define D  128
#define TEMP_INV 2.0f              // 1/TEMPERATURE
#define LOG2E 1.44269504088896340736f

typedef __bf16 bf16x8 __attribute__((ext_vector_type(8)));
typedef float  f32x4  __attribute__((ext_vector_type(4)));

__device__ __forceinline__ unsigned short f2bf(float f) {
    union { float f; unsigned u; } v; v.f = f;
    unsigned r = v.u + 0x7fffu + ((v.u >> 16) & 1u);
    return (unsigned short)(r >> 16);
}
__device__ __forceinline__ float bf2f(unsigned short h) {
    union { unsigned u; float f; } v; v.u = ((unsigned)h) << 16;
    return v.f;
}

// ---------- kernel 1: row L2-normalize (fp32) -> bf16 zn ----------
__global__ void k_norm(const float* __restrict__ z, unsigned short* __restrict__ zn) {
    int row  = blockIdx.x * 4 + (threadIdx.x >> 6);
    int lane = threadIdx.x & 63;
    const float2 v = ((const float2*)(z + (size_t)row * D))[lane];
    float ss = v.x * v.x + v.y * v.y;
    #pragma unroll
    for (int m = 1; m < 64; m <<= 1) ss += __shfl_xor(ss, m);
    float inv = 1.0f / fmaxf(sqrtf(ss), 1e-12f);
    ushort2 o; o.x = f2bf(v.x * inv); o.y = f2bf(v.y * inv);
    ((ushort2*)(zn + (size_t)row * D))[lane] = o;
}

// ---------- kernel 2: fused sim-tile GEMM + exp row-sum ----------
// tile 128x128, K=128 in one LDS stage, 4 waves (2x2), wave tile 64x64
__global__ __launch_bounds__(256, 2)
void k_sim(const unsigned short* __restrict__ zn, float* __restrict__ rowsum) {
    __shared__ unsigned short lsA[128 * 128];
    __shared__ unsigned short lsB[128 * 128];
    const int tileJ = blockIdx.x, tileI = blockIdx.y;
    const int tid = threadIdx.x;

    // stage A,B panels (32KB contiguous each), XOR-swizzled to kill
    // the 256B-stride bank conflict on ds_read_b128
    {
        const uint4* gA = (const uint4*)(zn + (size_t)tileI * 128 * D);
        const uint4* gB = (const uint4*)(zn + (size_t)tileJ * 128 * D);
        #pragma unroll
        for (int it = 0; it < 8; ++it) {
            int c = tid + 256 * it;              // 16B chunk id, 0..2047
            int d = c << 4;                      // linear byte offset
            int s = d ^ (((d >> 8) & 7) << 4);   // row = d>>8
            *(uint4*)((char*)lsA + s) = gA[c];
            *(uint4*)((char*)lsB + s) = gB[c];
        }
    }
    __syncthreads();

    const int lane = tid & 63, wid = tid >> 6;
    const int wr = wid >> 1, wc = wid & 1;       // 2x2 wave grid
    const int l16 = lane & 15, lg = lane >> 4;

    f32x4 acc[4][4];
    #pragma unroll
    for (int m = 0; m < 4; ++m)
        #pragma unroll
        for (int n = 0; n < 4; ++n)
            acc[m][n] = f32x4{0.f, 0.f, 0.f, 0.f};

    #pragma unroll
    for (int kk = 0; kk < 4; ++kk) {
        bf16x8 af[4], bfr[4];
        #pragma unroll
        for (int m = 0; m < 4; ++m) {
            int row = wr * 64 + m * 16 + l16;
            int d = row * 256 + kk * 64 + lg * 16;
            int s = d ^ ((row & 7) << 4);
            af[m] = *(const bf16x8*)((const char*)lsA + s);
        }
        #pragma unroll
        for (int n = 0; n < 4; ++n) {
            int row = wc * 64 + n * 16 + l16;
            int d = row * 256 + kk * 64 + lg * 16;
            int s = d ^ ((row & 7) << 4);
            bfr[n] = *(const bf16x8*)((const char*)lsB + s);
        }
        #pragma unroll
        for (int m = 0; m < 4; ++m)
            #pragma unroll
            for (int n = 0; n < 4; ++n)
                acc[m][n] = __builtin_amdgcn_mfma_f32_16x16x32_bf16(af[m], bfr[n], acc[m][n], 0, 0, 0);
    }

    // epilogue: rowsum += sum_j exp(2*cos - 2), diag masked
    const int giBase = tileI * 128 + wr * 64;
    const int gjBase = tileJ * 128 + wc * 64 + l16;
    #pragma unroll
    for (int m = 0; m < 4; ++m) {
        #pragma unroll
        for (int r = 0; r < 4; ++r) {
            int gi = giBase + m * 16 + lg * 4 + r;
            float rs = 0.f;
            #pragma unroll
            for (int n = 0; n < 4; ++n) {
                int gj = gjBase + n * 16;
                float e = exp2f(acc[m][n][r] * (TEMP_INV * LOG2E) - (TEMP_INV * LOG2E));
                rs += (gi == gj) ? 0.f : e;
            }
            rs += __shfl_xor(rs, 1);
            rs += __shfl_xor(rs, 2);
            rs += __shfl_xor(rs, 4);
            rs += __shfl_xor(rs, 8);
            if (l16 == 0) atomicAdd(&rowsum[gi], rs);
        }
    }
}

// ---------- kernel 3: per-row loss = -pos + 2 + ln(rowsum) ----------
__global__ void k_loss(const unsigned short* __restrict__ zn,
                       const float* __restrict__ rowsum,
                       float* __restrict__ loss) {
    int row  = blockIdx.x * 4 + (threadIdx.x >> 6);
    int lane = threadIdx.x & 63;
    int prow = row ^ 1;
    unsigned a = ((const unsigned*)(zn + (size_t)row  * D))[lane];
    unsigned b = ((const unsigned*)(zn + (size_t)prow * D))[lane];
    float d = bf2f((unsigned short)(a & 0xffff)) * bf2f((unsigned short)(b & 0xffff))
            + bf2f((unsigned short)(a >> 16))    * bf2f((unsigned short)(b >> 16));
    #pragma unroll
    for (int m = 1; m < 64; m <<= 1) d += __shfl_xor(d, m);
    if (lane == 0)
        loss[row] = -TEMP_INV * d + TEMP_INV + logf(rowsum[row]);
}

// ---------- kernel 4: mean over 16384 rows ----------
__global__ void k_reduce(const float* __restrict__ loss, float* __restrict__ out) {
    __shared__ float sm[256];
    int t = threadIdx.x;
    float s = 0.f;
    for (int i = t; i < N2; i += 256) s += loss[i];
    sm[t] = s;
    __syncthreads();
    #pragma unroll
    for (int w = 128; w > 0; w >>= 1) {
        if (t < w) sm[t] += sm[t + w];
        __syncthreads();
    }
    if (t == 0) out[0] = sm[0] * (1.0f / (float)N2);
}

extern "C" void kernel_launch(void* const* d_in, const int* in_sizes, int n_in,
                              void* d_out, int out_size, void* d_ws, size_t ws_size,
                              hipStream_t stream) {
    const float* z = (const float*)d_in[0];
    float* out = (float*)d_out;

    unsigned short* zn = (unsigned short*)d_ws;                       // 4 MiB
    float* rowsum = (float*)((char*)d_ws + (size_t)N2 * D * 2);       // 64 KiB
    float* loss   = rowsum + N2;                                      // 64 KiB

    hipMemsetAsync(rowsum, 0, N2 * sizeof(float), stream);
    k_norm<<<N2 / 4, 256, 0, stream>>>(z, zn);
    dim3 grid(N2 / 128, N2 / 128);
    k_sim<<<grid, 256, 0, stream>>>(zn, rowsum);
    k_loss<<<N2 / 4, 256, 0, stream>>>(zn, rowsum, loss);
    k_reduce<<<1, 256, 0, stream>>>(loss, out);
}

// Round 2
// 142.165 us; speedup vs baseline: 2.3684x; 2.3684x over previous
//
#include <hip/hip_runtime.h>
#include <hip/hip_bf16.h>

#define N2 16384
#define D  128
#define PANEL 32768                       // bytes per 128x128 bf16 panel
#define C1 2.88539008177792681472f        // (1/T)*log2(e) = 2*log2(e)

typedef __bf16 bf16x8 __attribute__((ext_vector_type(8)));
typedef float  f32x4  __attribute__((ext_vector_type(4)));

__device__ __forceinline__ unsigned short f2bf(float f) {
    union { float f; unsigned u; } v; v.f = f;
    unsigned r = v.u + 0x7fffu + ((v.u >> 16) & 1u);
    return (unsigned short)(r >> 16);
}
__device__ __forceinline__ float bf2f(unsigned short h) {
    union { unsigned u; float f; } v; v.u = ((unsigned)h) << 16;
    return v.f;
}

// stage one 32KB panel global->LDS via global_load_lds width=16.
// LDS dest is linear (wave-uniform base + lane*16); the XOR swizzle is
// applied to the GLOBAL source address (involution), so a swizzled read
// (byte ^ ((row&7)<<4)) returns the linear panel data. (rule #21)
__device__ __forceinline__ void stage_panel(const char* __restrict__ g,
                                            char* lds, int tid) {
    const int wid = tid >> 6, lane = tid & 63;
    #pragma unroll
    for (int i = 0; i < 8; ++i) {
        int off = (wid << 13) + (i << 10) + (lane << 4);
        int src = off ^ (((off >> 8) & 7) << 4);
        __builtin_amdgcn_global_load_lds(
            (const __attribute__((address_space(1))) unsigned*)(g + src),
            (__attribute__((address_space(3))) unsigned*)(lds + (wid << 13) + (i << 10)),
            16, 0, 0);
    }
}

// ---------- kernel 1: row L2-normalize (fp32) -> bf16 zn ----------
__global__ void k_norm(const float* __restrict__ z, unsigned short* __restrict__ zn) {
    int row  = blockIdx.x * 4 + (threadIdx.x >> 6);
    int lane = threadIdx.x & 63;
    const float2 v = ((const float2*)(z + (size_t)row * D))[lane];
    float ss = v.x * v.x + v.y * v.y;
    #pragma unroll
    for (int m = 1; m < 64; m <<= 1) ss += __shfl_xor(ss, m);
    float inv = 1.0f / fmaxf(sqrtf(ss), 1e-12f);
    ushort2 o; o.x = f2bf(v.x * inv); o.y = f2bf(v.y * inv);
    ((ushort2*)(zn + (size_t)row * D))[lane] = o;
}

// ---------- kernel 2: persistent-i fused sim GEMM + exp row-sum ----------
// block: i-tile (128 rows) x 16 j-tiles. A staged once -> regs. B dbuf'd.
__global__ __launch_bounds__(256, 2)
void k_sim(const unsigned short* __restrict__ zn, float* __restrict__ rowsum) {
    __shared__ unsigned short ls[2][PANEL / 2];
    char* ls0 = (char*)&ls[0][0];
    char* ls1 = (char*)&ls[1][0];

    const int tileI = blockIdx.y;
    const int jBase = blockIdx.x * 16;
    const int tid  = threadIdx.x;
    const int lane = tid & 63, wid = tid >> 6;
    const int wr = wid >> 1, wc = wid & 1;          // 2x2 wave grid, 64x64 each
    const int l16 = lane & 15, lg = lane >> 4;
    const char* znb = (const char*)zn;
    const f32x4 ZERO = {0.f, 0.f, 0.f, 0.f};

    // prologue: stage A -> ls0, B(j0) -> ls1
    stage_panel(znb + (size_t)tileI * PANEL, ls0, tid);
    stage_panel(znb + (size_t)jBase * PANEL, ls1, tid);
    asm volatile("s_waitcnt vmcnt(8)" ::: "memory");   // A landed (B0 may fly)
    __builtin_amdgcn_s_barrier();

    // A fragments -> registers (reused for all 16 j-tiles)
    bf16x8 af[4][4];                                   // [kk][m]
    #pragma unroll
    for (int kk = 0; kk < 4; ++kk)
        #pragma unroll
        for (int m = 0; m < 4; ++m) {
            int row = wr * 64 + m * 16 + l16;
            int d = row * 256 + kk * 64 + lg * 16;
            af[kk][m] = *(const bf16x8*)(ls0 + (d ^ ((row & 7) << 4)));
        }
    asm volatile("s_waitcnt lgkmcnt(0)" ::: "memory");
    __builtin_amdgcn_s_barrier();                      // ls0 now reusable

    float rs[4][4];
    #pragma unroll
    for (int m = 0; m < 4; ++m)
        #pragma unroll
        for (int r = 0; r < 4; ++r) rs[m][r] = 0.f;

    for (int t = 0; t < 16; ++t) {
        char* rbuf = (t & 1) ? ls0 : ls1;              // B(j_t)
        char* sbuf = (t & 1) ? ls1 : ls0;              // B(j_{t+1}) dest
        if (t < 15) {
            stage_panel(znb + (size_t)(jBase + t + 1) * PANEL, sbuf, tid);
            asm volatile("s_waitcnt vmcnt(8)" ::: "memory");  // j_t landed, j_{t+1} in flight
        } else {
            asm volatile("s_waitcnt vmcnt(0)" ::: "memory");
        }
        __builtin_amdgcn_s_barrier();

        bf16x8 bfr[4][4];                              // [kk][n]
        #pragma unroll
        for (int kk = 0; kk < 4; ++kk)
            #pragma unroll
            for (int n = 0; n < 4; ++n) {
                int row = wc * 64 + n * 16 + l16;
                int d = row * 256 + kk * 64 + lg * 16;
                bfr[kk][n] = *(const bf16x8*)(rbuf + (d ^ ((row & 7) << 4)));
            }
        asm volatile("s_waitcnt lgkmcnt(0)" ::: "memory");
        __builtin_amdgcn_s_barrier();                  // rbuf free for next stage

        f32x4 acc[4][4];
        #pragma unroll
        for (int m = 0; m < 4; ++m)
            #pragma unroll
            for (int n = 0; n < 4; ++n)
                acc[m][n] = __builtin_amdgcn_mfma_f32_16x16x32_bf16(af[0][m], bfr[0][n], ZERO, 0, 0, 0);
        #pragma unroll
        for (int kk = 1; kk < 4; ++kk)
            #pragma unroll
            for (int m = 0; m < 4; ++m)
                #pragma unroll
                for (int n = 0; n < 4; ++n)
                    acc[m][n] = __builtin_amdgcn_mfma_f32_16x16x32_bf16(af[kk][m], bfr[kk][n], acc[m][n], 0, 0, 0);

        // epilogue: rs += exp2(C1*cos - C1); diag mask only on the i==j tile
        if (jBase + t == tileI) {
            #pragma unroll
            for (int m = 0; m < 4; ++m)
                #pragma unroll
                for (int r = 0; r < 4; ++r) {
                    int li = wr * 64 + m * 16 + lg * 4 + r;
                    float a = 0.f;
                    #pragma unroll
                    for (int n = 0; n < 4; ++n) {
                        int lj = wc * 64 + n * 16 + l16;
                        float e = exp2f(acc[m][n][r] * C1 - C1);
                        a += (li == lj) ? 0.f : e;
                    }
                    rs[m][r] += a;
                }
        } else {
            #pragma unroll
            for (int m = 0; m < 4; ++m)
                #pragma unroll
                for (int r = 0; r < 4; ++r) {
                    float a = 0.f;
                    #pragma unroll
                    for (int n = 0; n < 4; ++n)
                        a += exp2f(acc[m][n][r] * C1 - C1);
                    rs[m][r] += a;
                }
        }
    }

    // final: reduce partial row-sums across the 16 column-lanes, one atomic/row
    #pragma unroll
    for (int m = 0; m < 4; ++m)
        #pragma unroll
        for (int r = 0; r < 4; ++r) {
            float v = rs[m][r];
            v += __shfl_xor(v, 1);
            v += __shfl_xor(v, 2);
            v += __shfl_xor(v, 4);
            v += __shfl_xor(v, 8);
            if (l16 == 0)
                atomicAdd(&rowsum[tileI * 128 + wr * 64 + m * 16 + lg * 4 + r], v);
        }
}

// ---------- kernel 3: per-row loss = -2*dot(zn_i, zn_{i^1}) + 2 + ln(rowsum) ----------
__global__ void k_loss(const unsigned short* __restrict__ zn,
                       const float* __restrict__ rowsum,
                       float* __restrict__ loss) {
    int row  = blockIdx.x * 4 + (threadIdx.x >> 6);
    int lane = threadIdx.x & 63;
    int prow = row ^ 1;
    unsigned a = ((const unsigned*)(zn + (size_t)row  * D))[lane];
    unsigned b = ((const unsigned*)(zn + (size_t)prow * D))[lane];
    float d = bf2f((unsigned short)(a & 0xffff)) * bf2f((unsigned short)(b & 0xffff))
            + bf2f((unsigned short)(a >> 16))    * bf2f((unsigned short)(b >> 16));
    #pragma unroll
    for (int m = 1; m < 64; m <<= 1) d += __shfl_xor(d, m);
    if (lane == 0)
        loss[row] = -2.0f * d + 2.0f + logf(rowsum[row]);
}

// ---------- kernel 4: mean ----------
__global__ void k_reduce(const float* __restrict__ loss, float* __restrict__ out) {
    __shared__ float sm[256];
    int t = threadIdx.x;
    float s = 0.f;
    for (int i = t; i < N2; i += 256) s += loss[i];
    sm[t] = s;
    __syncthreads();
    #pragma unroll
    for (int w = 128; w > 0; w >>= 1) {
        if (t < w) sm[t] += sm[t + w];
        __syncthreads();
    }
    if (t == 0) out[0] = sm[0] * (1.0f / (float)N2);
}

extern "C" void kernel_launch(void* const* d_in, const int* in_sizes, int n_in,
                              void* d_out, int out_size, void* d_ws, size_t ws_size,
                              hipStream_t stream) {
    const float* z = (const float*)d_in[0];
    float* out = (float*)d_out;

    unsigned short* zn = (unsigned short*)d_ws;                       // 4 MiB
    float* rowsum = (float*)((char*)d_ws + (size_t)N2 * D * 2);       // 64 KiB
    float* loss   = rowsum + N2;                                      // 64 KiB

    hipMemsetAsync(rowsum, 0, N2 * sizeof(float), stream);
    k_norm<<<N2 / 4, 256, 0, stream>>>(z, zn);
    dim3 grid(8, 128);                                                // j-chunks x i-tiles
    k_sim<<<grid, 256, 0, stream>>>(zn, rowsum);
    k_loss<<<N2 / 4, 256, 0, stream>>>(zn, rowsum, loss);
    k_reduce<<<1, 256, 0, stream>>>(loss, out);
}

// Round 3
// 68.504 us; speedup vs baseline: 4.9150x; 2.0753x over previous
//
#include <hip/hip_runtime.h>
#include <hip/hip_bf16.h>

#define N2 16384
#define D  128
#define PANEL 32768                       // bytes per 128x128 bf16 panel
#define C1   2.88539008177792681472f      // (1/T)*log2(e) = 2*log2(e)
#define SQC1 1.69864360258810896f         // sqrt(C1), folded into zn
#define LN2  0.69314718055994530942f

typedef __bf16 bf16x8 __attribute__((ext_vector_type(8)));
typedef float  f32x4  __attribute__((ext_vector_type(4)));

#if __has_builtin(__builtin_amdgcn_exp2f)
#define EXP2(x) __builtin_amdgcn_exp2f(x)
#else
#define EXP2(x) exp2f(x)
#endif

__device__ __forceinline__ unsigned short f2bf(float f) {
    union { float f; unsigned u; } v; v.f = f;
    unsigned r = v.u + 0x7fffu + ((v.u >> 16) & 1u);
    return (unsigned short)(r >> 16);
}

// stage one 32KB panel global->LDS via global_load_lds width=16.
// LDS dest linear; XOR swizzle applied to the GLOBAL source (involution),
// reads use byte ^ ((row&7)<<4). (rule #21)
__device__ __forceinline__ void stage_panel(const char* __restrict__ g,
                                            char* lds, int tid) {
    const int wid = tid >> 6, lane = tid & 63;
    #pragma unroll
    for (int i = 0; i < 8; ++i) {
        int off = (wid << 13) + (i << 10) + (lane << 4);
        int src = off ^ (((off >> 8) & 7) << 4);
        __builtin_amdgcn_global_load_lds(
            (const __attribute__((address_space(1))) unsigned*)(g + src),
            (__attribute__((address_space(3))) unsigned*)(lds + (wid << 13) + (i << 10)),
            16, 0, 0);
    }
}

// ---------- kernel 1: row L2-normalize (fp32) -> bf16 sqrt(C1)*zn ----------
__global__ void k_norm(const float* __restrict__ z, unsigned short* __restrict__ zn) {
    int row  = blockIdx.x * 4 + (threadIdx.x >> 6);
    int lane = threadIdx.x & 63;
    const float2 v = ((const float2*)(z + (size_t)row * D))[lane];
    float ss = v.x * v.x + v.y * v.y;
    #pragma unroll
    for (int m = 1; m < 64; m <<= 1) ss += __shfl_xor(ss, m);
    float inv = SQC1 / fmaxf(sqrtf(ss), 1e-12f);
    ushort2 o; o.x = f2bf(v.x * inv); o.y = f2bf(v.y * inv);
    ((ushort2*)(zn + (size_t)row * D))[lane] = o;
}

// ---------- kernel 2: symmetric fused sim GEMM + exp row/col sums ----------
// block (c, ti): tiles jt=(ti+s)&127 for s in [16c, 16c+16) (+s=64 for c==3,ti<64).
// s=0 tile: diagonal, mask self, row-sums only. s>0: row-sums AND col-sums.
__global__ __launch_bounds__(256, 2)
void k_sim(const unsigned short* __restrict__ zn, float* __restrict__ rowsum) {
    __shared__ unsigned short ls[2][PANEL / 2];
    char* ls0 = (char*)&ls[0][0];
    char* ls1 = (char*)&ls[1][0];

    const int tileI = blockIdx.y;
    const int sBase = blockIdx.x * 16;
    const int nt = (blockIdx.x == 3 && tileI < 64) ? 17 : 16;
    const int tid  = threadIdx.x;
    const int lane = tid & 63, wid = tid >> 6;
    const int wr = wid >> 1, wc = wid & 1;          // 2x2 wave grid, 64x64 each
    const int l16 = lane & 15, lg = lane >> 4;
    const char* znb = (const char*)zn;
    const f32x4 ZERO = {0.f, 0.f, 0.f, 0.f};

    // prologue: stage A(ti) -> ls0, B(s=sBase) -> ls1
    stage_panel(znb + (size_t)tileI * PANEL, ls0, tid);
    stage_panel(znb + (size_t)((tileI + sBase) & 127) * PANEL, ls1, tid);
    asm volatile("s_waitcnt vmcnt(8)" ::: "memory");   // A landed
    __builtin_amdgcn_s_barrier();

    // A fragments -> registers (reused for all tiles)
    bf16x8 af[4][4];                                   // [kk][m]
    #pragma unroll
    for (int kk = 0; kk < 4; ++kk)
        #pragma unroll
        for (int m = 0; m < 4; ++m) {
            int row = wr * 64 + m * 16 + l16;
            int d = row * 256 + kk * 64 + lg * 16;
            af[kk][m] = *(const bf16x8*)(ls0 + (d ^ ((row & 7) << 4)));
        }
    asm volatile("s_waitcnt lgkmcnt(0)" ::: "memory");
    __builtin_amdgcn_s_barrier();                      // ls0 now reusable

    float rs[4][4];
    #pragma unroll
    for (int m = 0; m < 4; ++m)
        #pragma unroll
        for (int r = 0; r < 4; ++r) rs[m][r] = 0.f;

    for (int t = 0; t < nt; ++t) {
        const int s  = sBase + t;
        const int jt = (tileI + s) & 127;
        char* rbuf = (t & 1) ? ls0 : ls1;              // B(s)
        char* sbuf = (t & 1) ? ls1 : ls0;              // B(s+1) dest
        if (t < nt - 1) {
            stage_panel(znb + (size_t)((tileI + s + 1) & 127) * PANEL, sbuf, tid);
            asm volatile("s_waitcnt vmcnt(8)" ::: "memory");  // B(s) landed
        } else {
            asm volatile("s_waitcnt vmcnt(0)" ::: "memory");
        }
        __builtin_amdgcn_s_barrier();

        bf16x8 bfr[4][4];                              // [kk][n]
        #pragma unroll
        for (int kk = 0; kk < 4; ++kk)
            #pragma unroll
            for (int n = 0; n < 4; ++n) {
                int row = wc * 64 + n * 16 + l16;
                int d = row * 256 + kk * 64 + lg * 16;
                bfr[kk][n] = *(const bf16x8*)(rbuf + (d ^ ((row & 7) << 4)));
            }
        asm volatile("s_waitcnt lgkmcnt(0)" ::: "memory");
        __builtin_amdgcn_s_barrier();                  // rbuf free for next stage

        f32x4 acc[4][4];
        #pragma unroll
        for (int m = 0; m < 4; ++m)
            #pragma unroll
            for (int n = 0; n < 4; ++n)
                acc[m][n] = __builtin_amdgcn_mfma_f32_16x16x32_bf16(af[0][m], bfr[0][n], ZERO, 0, 0, 0);
        #pragma unroll
        for (int kk = 1; kk < 4; ++kk)
            #pragma unroll
            for (int m = 0; m < 4; ++m)
                #pragma unroll
                for (int n = 0; n < 4; ++n)
                    acc[m][n] = __builtin_amdgcn_mfma_f32_16x16x32_bf16(af[kk][m], bfr[kk][n], acc[m][n], 0, 0, 0);

        // epilogue: e = exp2(acc) = exp(sim); rows accumulate in regs,
        // cols flushed per tile (jt changes every tile).
        if (s == 0) {
            // diagonal tile: mask self-sim, row sums only
            #pragma unroll
            for (int m = 0; m < 4; ++m)
                #pragma unroll
                for (int r = 0; r < 4; ++r) {
                    int li = wr * 64 + m * 16 + lg * 4 + r;
                    float a = 0.f;
                    #pragma unroll
                    for (int n = 0; n < 4; ++n) {
                        int lj = wc * 64 + n * 16 + l16;
                        float e = EXP2(acc[m][n][r]);
                        a += (li == lj) ? 0.f : e;
                    }
                    rs[m][r] += a;
                }
        } else {
            float cs[4] = {0.f, 0.f, 0.f, 0.f};
            #pragma unroll
            for (int m = 0; m < 4; ++m)
                #pragma unroll
                for (int r = 0; r < 4; ++r) {
                    float a = 0.f;
                    #pragma unroll
                    for (int n = 0; n < 4; ++n) {
                        float e = EXP2(acc[m][n][r]);
                        a += e;
                        cs[n] += e;
                    }
                    rs[m][r] += a;
                }
            // column flush: reduce over the 4 lg row-groups of this wave
            #pragma unroll
            for (int n = 0; n < 4; ++n) {
                float v = cs[n];
                v += __shfl_xor(v, 16);
                v += __shfl_xor(v, 32);
                if (lg == 0)
                    atomicAdd(&rowsum[jt * 128 + wc * 64 + n * 16 + l16], v);
            }
        }
    }

    // final: row sums -> reduce across 16 column-lanes, one atomic/row
    #pragma unroll
    for (int m = 0; m < 4; ++m)
        #pragma unroll
        for (int r = 0; r < 4; ++r) {
            float v = rs[m][r];
            v += __shfl_xor(v, 1);
            v += __shfl_xor(v, 2);
            v += __shfl_xor(v, 4);
            v += __shfl_xor(v, 8);
            if (l16 == 0)
                atomicAdd(&rowsum[tileI * 128 + wr * 64 + m * 16 + lg * 4 + r], v);
        }
}

// ---------- kernel 3: fused loss + mean ----------
// mean loss = (1/N2) * [ sum_i ln(rowsum_i) - ln2 * sum_{i,k} zn'[i][k]*zn'[i^1][k] ]
__global__ void k_loss_reduce(const unsigned short* __restrict__ zn,
                              const float* __restrict__ rowsum,
                              float* __restrict__ out) {
    const int tid = threadIdx.x + blockIdx.x * 256;   // 64 blocks x 256
    float p = 0.f;
    const bf16x8* v8 = (const bf16x8*)zn;
    for (int v = tid; v < N2 * D / 8; v += 64 * 256) {
        bf16x8 a = v8[v];
        bf16x8 b = v8[v ^ 16];                        // row i^1, same k-slice
        #pragma unroll
        for (int e = 0; e < 8; ++e) p += (float)a[e] * (float)b[e];
    }
    float part = logf(rowsum[tid]) - LN2 * p;         // exactly one row per thread

    // block reduce
    __shared__ float sm[4];
    #pragma unroll
    for (int m = 1; m < 64; m <<= 1) part += __shfl_xor(part, m);
    if ((threadIdx.x & 63) == 0) sm[threadIdx.x >> 6] = part;
    __syncthreads();
    if (threadIdx.x == 0)
        atomicAdd(out, (sm[0] + sm[1] + sm[2] + sm[3]) * (1.0f / (float)N2));
}

extern "C" void kernel_launch(void* const* d_in, const int* in_sizes, int n_in,
                              void* d_out, int out_size, void* d_ws, size_t ws_size,
                              hipStream_t stream) {
    const float* z = (const float*)d_in[0];
    float* out = (float*)d_out;

    unsigned short* zn = (unsigned short*)d_ws;                       // 4 MiB
    float* rowsum = (float*)((char*)d_ws + (size_t)N2 * D * 2);       // 64 KiB

    hipMemsetAsync(rowsum, 0, N2 * sizeof(float), stream);
    hipMemsetAsync(out, 0, sizeof(float), stream);
    k_norm<<<N2 / 4, 256, 0, stream>>>(z, zn);
    dim3 grid(4, 128);                                                // s-chunks x i-tiles
    k_sim<<<grid, 256, 0, stream>>>(zn, rowsum);
    k_loss_reduce<<<64, 256, 0, stream>>>(zn, rowsum, out);
}